// Round 5
// baseline (207.190 us; speedup 1.0000x reference)
//
#include <hip/hip_runtime.h>

// SparseMoE: T=4096, D=1024, E=8, H=2048, top_k=2.
// R5: 256x256 tile, BK=64, 8 waves, 2-phase dbuf (m248v2's 666 TF grouped
// geometry). LDS 128KB -> 1 block/CU; 64 MFMA/wave per barrier amortizes the
// vmcnt(0) drain. Swizzled global_load_lds staging, atomic scatter epilogue.

#define NTOK 4096
#define DIM  1024
#define NEXP 8
#define HID  2048

#define BM 256
#define BN 256
#define BK 64

using u16    = unsigned short;
using u16x4  = __attribute__((ext_vector_type(4))) unsigned short;
using u16x8  = __attribute__((ext_vector_type(8))) unsigned short;
using bf16x8 = __attribute__((ext_vector_type(8))) __bf16;
using f32x4  = __attribute__((ext_vector_type(4))) float;

typedef const __attribute__((address_space(1))) unsigned char* gas1p;
typedef __attribute__((address_space(3))) unsigned char* gas3p;

__device__ __forceinline__ void gload16(void* lds, const void* g) {
  __builtin_amdgcn_global_load_lds((gas1p)g, (gas3p)lds, 16, 0, 0);
}

__device__ inline u16 f2bf(float f) {
  union { float f; unsigned u; } v; v.f = f;
  unsigned r = v.u + 0x7fffu + ((v.u >> 16) & 1u);  // RNE, no NaN in this data
  return (u16)(r >> 16);
}

// ---------------- fp32 -> bf16 bulk convert (8 elems/thread) -----------------
__global__ __launch_bounds__(256) void convert_bf16(
    const float* __restrict__ in, u16* __restrict__ out) {
  int i = blockIdx.x * 256 + threadIdx.x;
  const float4* p = (const float4*)in + (size_t)i * 2;
  float4 a = p[0], b = p[1];
  u16x8 r;
  r[0] = f2bf(a.x); r[1] = f2bf(a.y); r[2] = f2bf(a.z); r[3] = f2bf(a.w);
  r[4] = f2bf(b.x); r[5] = f2bf(b.y); r[6] = f2bf(b.z); r[7] = f2bf(b.w);
  *((u16x8*)out + i) = r;
}

// -------- gating: fp64 logits, softmax, top-2 -> ws; also emits xbf ----------
__global__ __launch_bounds__(256) void gate_kernel(
    const float* __restrict__ x, const float* __restrict__ gW,
    const float* __restrict__ gb, float* __restrict__ probs,
    int* __restrict__ top2, u16* __restrict__ xbf) {
  const int wave = threadIdx.x >> 6;
  const int lane = threadIdx.x & 63;
  const int t = blockIdx.x * 4 + wave;

  const float4* xrow = (const float4*)(x + (size_t)t * DIM);
  double acc[NEXP];
#pragma unroll
  for (int e = 0; e < NEXP; ++e) acc[e] = 0.0;

#pragma unroll
  for (int c = 0; c < 4; ++c) {
    int idx = c * 64 + lane;          // float4 index; elems 4*idx..4*idx+3
    float4 xv = xrow[idx];
    u16x4 bv;
    bv[0] = f2bf(xv.x); bv[1] = f2bf(xv.y); bv[2] = f2bf(xv.z); bv[3] = f2bf(xv.w);
    *(u16x4*)(xbf + (size_t)t * DIM + 4 * idx) = bv;   // fused convert_x
#pragma unroll
    for (int e = 0; e < NEXP; ++e) {
      float4 wv = ((const float4*)(gW + (size_t)e * DIM))[idx];
      acc[e] += (double)xv.x * wv.x + (double)xv.y * wv.y +
                (double)xv.z * wv.z + (double)xv.w * wv.w;
    }
  }
#pragma unroll
  for (int e = 0; e < NEXP; ++e) {
    double v = acc[e];
#pragma unroll
    for (int off = 32; off > 0; off >>= 1) v += __shfl_down(v, off);
    acc[e] = v;
  }

  if (lane == 0) {
    double logits[NEXP];
#pragma unroll
    for (int e = 0; e < NEXP; ++e) logits[e] = acc[e] + (double)gb[e];
    double m = logits[0];
#pragma unroll
    for (int e = 1; e < NEXP; ++e) m = fmax(m, logits[e]);
    double p[NEXP], s = 0.0;
#pragma unroll
    for (int e = 0; e < NEXP; ++e) { p[e] = exp(logits[e] - m); s += p[e]; }
#pragma unroll
    for (int e = 0; e < NEXP; ++e) p[e] /= s;

    int i1 = 0;
#pragma unroll
    for (int e = 1; e < NEXP; ++e) if (p[e] > p[i1]) i1 = e;
    int i2 = (i1 == 0) ? 1 : 0;
#pragma unroll
    for (int e = 0; e < NEXP; ++e) {
      if (e != i1 && p[e] > p[i2]) i2 = e;
    }

#pragma unroll
    for (int e = 0; e < NEXP; ++e) probs[(size_t)t * NEXP + e] = (float)p[e];
    top2[t] = i1 | (i2 << 4);
  }
}

// ------- route: per-expert stable compaction (ballot prefix) + fp64 variance -
__global__ __launch_bounds__(256) void route_kernel(
    const float* __restrict__ probs, const int* __restrict__ top2,
    int* __restrict__ counts, int* __restrict__ lists,
    float* __restrict__ var_out) {
  const int e = blockIdx.x;
  const int tid = threadIdx.x;
  const int lane = tid & 63;
  const int wave = tid >> 6;

  __shared__ int wsum[4];
  __shared__ double ds[4], dq[4];

  double s = 0.0, q = 0.0;
  int base = 0;

  for (int c = 0; c < NTOK / 256; ++c) {
    int t = c * 256 + tid;
    float p = probs[(size_t)t * NEXP + e];
    s += (double)p;
    q += (double)p * (double)p;

    int m = top2[t];
    bool f = ((m & 15) == e) || (((m >> 4) & 15) == e);
    unsigned long long bal = __ballot(f);
    int before = __popcll(bal & ((1ull << lane) - 1ull));
    if (lane == 0) wsum[wave] = __popcll(bal);
    __syncthreads();
    int woff = 0;
#pragma unroll
    for (int w = 0; w < 4; ++w) if (w < wave) woff += wsum[w];
    int ctotal = wsum[0] + wsum[1] + wsum[2] + wsum[3];
    if (f) lists[e * NTOK + base + woff + before] = t;
    base += ctotal;
    __syncthreads();
  }
  if (tid == 0) counts[e] = base;

#pragma unroll
  for (int off = 32; off > 0; off >>= 1) {
    s += __shfl_down(s, off);
    q += __shfl_down(q, off);
  }
  if (lane == 0) { ds[wave] = s; dq[wave] = q; }
  __syncthreads();
  if (tid == 0) {
    double S = ds[0] + ds[1] + ds[2] + ds[3];
    double Q = dq[0] + dq[1] + dq[2] + dq[3];
    var_out[e] = (float)((Q - S * S / (double)NTOK) / (double)(NTOK - 1));
  }
}

// ---- gathered expert GEMM: 256x256 tile, 8 waves, dbuf 2-phase, swizzled ----
// LDS per buffer: A [256 rows][64 cols] bf16 row-major (128 B/row), 16B-chunk
// swizzle stored_c16 = c16 ^ (row&7); B identical. global_load_lds writes LDS
// linearly; global source carries the inverse (same) XOR.
__global__ __launch_bounds__(512, 2) void expert_gemm(
    const u16* __restrict__ xbf, const u16* __restrict__ wbf,
    const float* __restrict__ eb, const int* __restrict__ counts,
    const int* __restrict__ lists, float* __restrict__ out) {
  __shared__ u16 As[2][BM * BK];   // 2 x 32 KB
  __shared__ u16 Bs[2][BN * BK];   // 2 x 32 KB
  __shared__ int tok[BM];

  const int bid = blockIdx.x;
  const int e  = bid >> 7;          // 128 blocks/expert: 16 rb x 8 cb
  const int rb = (bid >> 3) & 15;
  const int cb = bid & 7;
  const int cnt = counts[e];
  if (rb * BM >= cnt) return;

  const int tid  = threadIdx.x;
  const int wave = tid >> 6;
  const int lane = tid & 63;

  if (tid < BM) {
    int gi = rb * BM + tid;
    tok[tid] = (gi < cnt) ? lists[e * NTOK + gi] : -1;
  }
  __syncthreads();

  // ---- staging precompute: 4 A-issues + 4 B-issues of 16B per thread ----
  // chunk i = j*512 + tid covers [256 rows][8 chunks]; row=i>>3, c16s=i&7.
  const u16* asrc[4];
  const u16* bsrc[4];
  int ldsoff[4];
#pragma unroll
  for (int j = 0; j < 4; ++j) {
    const int idx  = j * 512 + tid;
    const int row  = idx >> 3;
    const int c16  = (idx & 7) ^ (row & 7);       // inverse swizzle on source
    int tr = tok[row]; if (tr < 0) tr = 0;        // clamped; row discarded later
    asrc[j] = xbf + (size_t)tr * DIM + c16 * 8;
    bsrc[j] = wbf + ((size_t)e * HID + (size_t)cb * BN + row) * DIM + c16 * 8;
    ldsoff[j] = j * 4096 + wave * 512;            // wave-uniform base (u16 units)
  }

#define STAGE(buf, k0)                                                        \
  do {                                                                        \
    _Pragma("unroll")                                                         \
    for (int j = 0; j < 4; ++j) gload16(&As[buf][ldsoff[j]], asrc[j] + (k0)); \
    _Pragma("unroll")                                                         \
    for (int j = 0; j < 4; ++j) gload16(&Bs[buf][ldsoff[j]], bsrc[j] + (k0)); \
  } while (0)

  // ---- wave -> output sub-tile: 2 (M) x 4 (N) waves, each 128x64 ----
  const int wmi = wave >> 2;        // 0..1
  const int wni = wave & 3;         // 0..3
  const int lr  = lane & 15;
  const int hk  = lane >> 4;        // 0..3

  f32x4 acc[8][4];
#pragma unroll
  for (int m = 0; m < 8; ++m)
#pragma unroll
    for (int n = 0; n < 4; ++n) acc[m][n] = (f32x4)(0.0f);

  STAGE(0, 0);
  __syncthreads();                  // drains vmcnt(0) + barrier

  int cur = 0;
  for (int kt = 0; kt < DIM / BK; ++kt) {
    if (kt + 1 < DIM / BK) STAGE(cur ^ 1, (kt + 1) * BK);  // prefetch next

    // B fragments for both kk halves (32 VGPR)
    bf16x8 fb[2][4];
#pragma unroll
    for (int kk = 0; kk < 2; ++kk)
#pragma unroll
      for (int n = 0; n < 4; ++n) {
        const int row = wni * 64 + n * 16 + lr;
        const int c16 = (kk * 4 + hk) ^ (row & 7);
        fb[kk][n] = *(const bf16x8*)&Bs[cur][row * 64 + c16 * 8];
      }

    // rolling A fragments: 8 VGPR live at a time
#pragma unroll
    for (int m = 0; m < 8; ++m) {
      const int row = wmi * 128 + m * 16 + lr;
      const int c0 = (0 + hk) ^ (row & 7);
      const int c1 = (4 + hk) ^ (row & 7);
      bf16x8 fa0 = *(const bf16x8*)&As[cur][row * 64 + c0 * 8];
      bf16x8 fa1 = *(const bf16x8*)&As[cur][row * 64 + c1 * 8];
#pragma unroll
      for (int n = 0; n < 4; ++n)
        acc[m][n] = __builtin_amdgcn_mfma_f32_16x16x32_bf16(
            fa0, fb[0][n], acc[m][n], 0, 0, 0);
#pragma unroll
      for (int n = 0; n < 4; ++n)
        acc[m][n] = __builtin_amdgcn_mfma_f32_16x16x32_bf16(
            fa1, fb[1][n], acc[m][n], 0, 0, 0);
    }

    __syncthreads();                // one vmcnt(0)-drain + barrier per K-tile
    cur ^= 1;
  }
#undef STAGE

  // epilogue: out[token, h] += 0.5*(dot + bias)  (2 commutative adds/elem)
#pragma unroll
  for (int n = 0; n < 4; ++n) {
    const int hcol = cb * BN + wni * 64 + n * 16 + lr;
    const float bias = eb[e * HID + hcol];
#pragma unroll
    for (int m = 0; m < 8; ++m) {
#pragma unroll
      for (int i = 0; i < 4; ++i) {
        int rloc = wmi * 128 + m * 16 + hk * 4 + i;   // C/D: row=(lane>>4)*4+i
        int tr = tok[rloc];
        if (tr >= 0)
          atomicAdd(&out[(size_t)tr * HID + hcol], 0.5f * (acc[m][n][i] + bias));
      }
    }
  }
}

extern "C" void kernel_launch(void* const* d_in, const int* in_sizes, int n_in,
                              void* d_out, int out_size, void* d_ws, size_t ws_size,
                              hipStream_t stream) {
  const float* x  = (const float*)d_in[0];   // [4096,1024]
  const float* gW = (const float*)d_in[1];   // [8,1024]
  const float* gb = (const float*)d_in[2];   // [8]
  const float* eW = (const float*)d_in[3];   // [8,2048,1024]
  const float* eb = (const float*)d_in[4];   // [8,2048]

  float* out = (float*)d_out;
  float* var_out = out + (size_t)NTOK * HID;

  // ws layout
  char* ws = (char*)d_ws;
  int*   counts = (int*)ws;                                   // 32 B
  int*   lists  = (int*)(ws + 1024);                          // 128 KB
  float* probs  = (float*)(ws + 1024 + 131072);               // 128 KB
  int*   top2   = (int*)(ws + 1024 + 2 * 131072);             // 16 KB
  u16*   xbf    = (u16*)(ws + 1024 + 2 * 131072 + 16384);     // 8 MB
  u16*   wbf    = (u16*)((char*)xbf + (size_t)NTOK * DIM * 2);// 32 MB

  hipMemsetAsync(d_out, 0, (size_t)out_size * sizeof(float), stream);

  convert_bf16<<<(NEXP * HID * DIM) / (256 * 8), 256, 0, stream>>>(eW, wbf);
  gate_kernel<<<NTOK / 4, 256, 0, stream>>>(x, gW, gb, probs, top2, xbf);
  route_kernel<<<NEXP, 256, 0, stream>>>(probs, top2, counts, lists, var_out);
  expert_gemm<<<NEXP * (NTOK / BM) * (HID / BN), 512, 0, stream>>>(
      xbf, wbf, eb, counts, lists, out);
}

// Round 6
// 207.037 us; speedup vs baseline: 1.0007x; 1.0007x over previous
//
#include <hip/hip_runtime.h>

// SparseMoE: T=4096, D=1024, E=8, H=2048, top_k=2.
// R5: 256x256 tile, BK=64, 8 waves, 2-phase dbuf (m248v2's 666 TF grouped
// geometry). LDS 128KB -> 1 block/CU; 64 MFMA/wave per barrier amortizes the
// vmcnt(0) drain. Swizzled global_load_lds staging, atomic scatter epilogue.

#define NTOK 4096
#define DIM  1024
#define NEXP 8
#define HID  2048

#define BM 256
#define BN 256
#define BK 64

using u16    = unsigned short;
using u16x4  = __attribute__((ext_vector_type(4))) unsigned short;
using u16x8  = __attribute__((ext_vector_type(8))) unsigned short;
using bf16x8 = __attribute__((ext_vector_type(8))) __bf16;
using f32x4  = __attribute__((ext_vector_type(4))) float;

typedef const __attribute__((address_space(1))) unsigned char* gas1p;
typedef __attribute__((address_space(3))) unsigned char* gas3p;

__device__ __forceinline__ void gload16(void* lds, const void* g) {
  __builtin_amdgcn_global_load_lds((gas1p)g, (gas3p)lds, 16, 0, 0);
}

__device__ inline u16 f2bf(float f) {
  union { float f; unsigned u; } v; v.f = f;
  unsigned r = v.u + 0x7fffu + ((v.u >> 16) & 1u);  // RNE, no NaN in this data
  return (u16)(r >> 16);
}

// ---------------- fp32 -> bf16 bulk convert (8 elems/thread) -----------------
__global__ __launch_bounds__(256) void convert_bf16(
    const float* __restrict__ in, u16* __restrict__ out) {
  int i = blockIdx.x * 256 + threadIdx.x;
  const float4* p = (const float4*)in + (size_t)i * 2;
  float4 a = p[0], b = p[1];
  u16x8 r;
  r[0] = f2bf(a.x); r[1] = f2bf(a.y); r[2] = f2bf(a.z); r[3] = f2bf(a.w);
  r[4] = f2bf(b.x); r[5] = f2bf(b.y); r[6] = f2bf(b.z); r[7] = f2bf(b.w);
  *((u16x8*)out + i) = r;
}

// -------- gating: fp64 logits, softmax, top-2 -> ws; also emits xbf ----------
__global__ __launch_bounds__(256) void gate_kernel(
    const float* __restrict__ x, const float* __restrict__ gW,
    const float* __restrict__ gb, float* __restrict__ probs,
    int* __restrict__ top2, u16* __restrict__ xbf) {
  const int wave = threadIdx.x >> 6;
  const int lane = threadIdx.x & 63;
  const int t = blockIdx.x * 4 + wave;

  const float4* xrow = (const float4*)(x + (size_t)t * DIM);
  double acc[NEXP];
#pragma unroll
  for (int e = 0; e < NEXP; ++e) acc[e] = 0.0;

#pragma unroll
  for (int c = 0; c < 4; ++c) {
    int idx = c * 64 + lane;          // float4 index; elems 4*idx..4*idx+3
    float4 xv = xrow[idx];
    u16x4 bv;
    bv[0] = f2bf(xv.x); bv[1] = f2bf(xv.y); bv[2] = f2bf(xv.z); bv[3] = f2bf(xv.w);
    *(u16x4*)(xbf + (size_t)t * DIM + 4 * idx) = bv;   // fused convert_x
#pragma unroll
    for (int e = 0; e < NEXP; ++e) {
      float4 wv = ((const float4*)(gW + (size_t)e * DIM))[idx];
      acc[e] += (double)xv.x * wv.x + (double)xv.y * wv.y +
                (double)xv.z * wv.z + (double)xv.w * wv.w;
    }
  }
#pragma unroll
  for (int e = 0; e < NEXP; ++e) {
    double v = acc[e];
#pragma unroll
    for (int off = 32; off > 0; off >>= 1) v += __shfl_down(v, off);
    acc[e] = v;
  }

  if (lane == 0) {
    double logits[NEXP];
#pragma unroll
    for (int e = 0; e < NEXP; ++e) logits[e] = acc[e] + (double)gb[e];
    double m = logits[0];
#pragma unroll
    for (int e = 1; e < NEXP; ++e) m = fmax(m, logits[e]);
    double p[NEXP], s = 0.0;
#pragma unroll
    for (int e = 0; e < NEXP; ++e) { p[e] = exp(logits[e] - m); s += p[e]; }
#pragma unroll
    for (int e = 0; e < NEXP; ++e) p[e] /= s;

    int i1 = 0;
#pragma unroll
    for (int e = 1; e < NEXP; ++e) if (p[e] > p[i1]) i1 = e;
    int i2 = (i1 == 0) ? 1 : 0;
#pragma unroll
    for (int e = 0; e < NEXP; ++e) {
      if (e != i1 && p[e] > p[i2]) i2 = e;
    }

#pragma unroll
    for (int e = 0; e < NEXP; ++e) probs[(size_t)t * NEXP + e] = (float)p[e];
    top2[t] = i1 | (i2 << 4);
  }
}

// ------- route: per-expert stable compaction (ballot prefix) + fp64 variance -
__global__ __launch_bounds__(256) void route_kernel(
    const float* __restrict__ probs, const int* __restrict__ top2,
    int* __restrict__ counts, int* __restrict__ lists,
    float* __restrict__ var_out) {
  const int e = blockIdx.x;
  const int tid = threadIdx.x;
  const int lane = tid & 63;
  const int wave = tid >> 6;

  __shared__ int wsum[4];
  __shared__ double ds[4], dq[4];

  double s = 0.0, q = 0.0;
  int base = 0;

  for (int c = 0; c < NTOK / 256; ++c) {
    int t = c * 256 + tid;
    float p = probs[(size_t)t * NEXP + e];
    s += (double)p;
    q += (double)p * (double)p;

    int m = top2[t];
    bool f = ((m & 15) == e) || (((m >> 4) & 15) == e);
    unsigned long long bal = __ballot(f);
    int before = __popcll(bal & ((1ull << lane) - 1ull));
    if (lane == 0) wsum[wave] = __popcll(bal);
    __syncthreads();
    int woff = 0;
#pragma unroll
    for (int w = 0; w < 4; ++w) if (w < wave) woff += wsum[w];
    int ctotal = wsum[0] + wsum[1] + wsum[2] + wsum[3];
    if (f) lists[e * NTOK + base + woff + before] = t;
    base += ctotal;
    __syncthreads();
  }
  if (tid == 0) counts[e] = base;

#pragma unroll
  for (int off = 32; off > 0; off >>= 1) {
    s += __shfl_down(s, off);
    q += __shfl_down(q, off);
  }
  if (lane == 0) { ds[wave] = s; dq[wave] = q; }
  __syncthreads();
  if (tid == 0) {
    double S = ds[0] + ds[1] + ds[2] + ds[3];
    double Q = dq[0] + dq[1] + dq[2] + dq[3];
    var_out[e] = (float)((Q - S * S / (double)NTOK) / (double)(NTOK - 1));
  }
}

// ---- gathered expert GEMM: 256x256 tile, 8 waves, dbuf 2-phase, swizzled ----
// LDS per buffer: A [256 rows][64 cols] bf16 row-major (128 B/row), 16B-chunk
// swizzle stored_c16 = c16 ^ (row&7); B identical. global_load_lds writes LDS
// linearly; global source carries the inverse (same) XOR.
__global__ __launch_bounds__(512, 2) void expert_gemm(
    const u16* __restrict__ xbf, const u16* __restrict__ wbf,
    const float* __restrict__ eb, const int* __restrict__ counts,
    const int* __restrict__ lists, float* __restrict__ out) {
  __shared__ u16 As[2][BM * BK];   // 2 x 32 KB
  __shared__ u16 Bs[2][BN * BK];   // 2 x 32 KB
  __shared__ int tok[BM];

  const int bid = blockIdx.x;
  const int e  = bid >> 7;          // 128 blocks/expert: 16 rb x 8 cb
  const int rb = (bid >> 3) & 15;
  const int cb = bid & 7;
  const int cnt = counts[e];
  if (rb * BM >= cnt) return;

  const int tid  = threadIdx.x;
  const int wave = tid >> 6;
  const int lane = tid & 63;

  if (tid < BM) {
    int gi = rb * BM + tid;
    tok[tid] = (gi < cnt) ? lists[e * NTOK + gi] : -1;
  }
  __syncthreads();

  // ---- staging precompute: 4 A-issues + 4 B-issues of 16B per thread ----
  // chunk i = j*512 + tid covers [256 rows][8 chunks]; row=i>>3, c16s=i&7.
  const u16* asrc[4];
  const u16* bsrc[4];
  int ldsoff[4];
#pragma unroll
  for (int j = 0; j < 4; ++j) {
    const int idx  = j * 512 + tid;
    const int row  = idx >> 3;
    const int c16  = (idx & 7) ^ (row & 7);       // inverse swizzle on source
    int tr = tok[row]; if (tr < 0) tr = 0;        // clamped; row discarded later
    asrc[j] = xbf + (size_t)tr * DIM + c16 * 8;
    bsrc[j] = wbf + ((size_t)e * HID + (size_t)cb * BN + row) * DIM + c16 * 8;
    ldsoff[j] = j * 4096 + wave * 512;            // wave-uniform base (u16 units)
  }

#define STAGE(buf, k0)                                                        \
  do {                                                                        \
    _Pragma("unroll")                                                         \
    for (int j = 0; j < 4; ++j) gload16(&As[buf][ldsoff[j]], asrc[j] + (k0)); \
    _Pragma("unroll")                                                         \
    for (int j = 0; j < 4; ++j) gload16(&Bs[buf][ldsoff[j]], bsrc[j] + (k0)); \
  } while (0)

  // ---- wave -> output sub-tile: 2 (M) x 4 (N) waves, each 128x64 ----
  const int wmi = wave >> 2;        // 0..1
  const int wni = wave & 3;         // 0..3
  const int lr  = lane & 15;
  const int hk  = lane >> 4;        // 0..3

  f32x4 acc[8][4];
#pragma unroll
  for (int m = 0; m < 8; ++m)
#pragma unroll
    for (int n = 0; n < 4; ++n) acc[m][n] = (f32x4)(0.0f);

  STAGE(0, 0);
  __syncthreads();                  // drains vmcnt(0) + barrier

  int cur = 0;
  for (int kt = 0; kt < DIM / BK; ++kt) {
    if (kt + 1 < DIM / BK) STAGE(cur ^ 1, (kt + 1) * BK);  // prefetch next

    // B fragments for both kk halves (32 VGPR)
    bf16x8 fb[2][4];
#pragma unroll
    for (int kk = 0; kk < 2; ++kk)
#pragma unroll
      for (int n = 0; n < 4; ++n) {
        const int row = wni * 64 + n * 16 + lr;
        const int c16 = (kk * 4 + hk) ^ (row & 7);
        fb[kk][n] = *(const bf16x8*)&Bs[cur][row * 64 + c16 * 8];
      }

    // rolling A fragments: 8 VGPR live at a time
#pragma unroll
    for (int m = 0; m < 8; ++m) {
      const int row = wmi * 128 + m * 16 + lr;
      const int c0 = (0 + hk) ^ (row & 7);
      const int c1 = (4 + hk) ^ (row & 7);
      bf16x8 fa0 = *(const bf16x8*)&As[cur][row * 64 + c0 * 8];
      bf16x8 fa1 = *(const bf16x8*)&As[cur][row * 64 + c1 * 8];
#pragma unroll
      for (int n = 0; n < 4; ++n)
        acc[m][n] = __builtin_amdgcn_mfma_f32_16x16x32_bf16(
            fa0, fb[0][n], acc[m][n], 0, 0, 0);
#pragma unroll
      for (int n = 0; n < 4; ++n)
        acc[m][n] = __builtin_amdgcn_mfma_f32_16x16x32_bf16(
            fa1, fb[1][n], acc[m][n], 0, 0, 0);
    }

    __syncthreads();                // one vmcnt(0)-drain + barrier per K-tile
    cur ^= 1;
  }
#undef STAGE

  // epilogue: out[token, h] += 0.5*(dot + bias)  (2 commutative adds/elem)
#pragma unroll
  for (int n = 0; n < 4; ++n) {
    const int hcol = cb * BN + wni * 64 + n * 16 + lr;
    const float bias = eb[e * HID + hcol];
#pragma unroll
    for (int m = 0; m < 8; ++m) {
#pragma unroll
      for (int i = 0; i < 4; ++i) {
        int rloc = wmi * 128 + m * 16 + hk * 4 + i;   // C/D: row=(lane>>4)*4+i
        int tr = tok[rloc];
        if (tr >= 0)
          atomicAdd(&out[(size_t)tr * HID + hcol], 0.5f * (acc[m][n][i] + bias));
      }
    }
  }
}

extern "C" void kernel_launch(void* const* d_in, const int* in_sizes, int n_in,
                              void* d_out, int out_size, void* d_ws, size_t ws_size,
                              hipStream_t stream) {
  const float* x  = (const float*)d_in[0];   // [4096,1024]
  const float* gW = (const float*)d_in[1];   // [8,1024]
  const float* gb = (const float*)d_in[2];   // [8]
  const float* eW = (const float*)d_in[3];   // [8,2048,1024]
  const float* eb = (const float*)d_in[4];   // [8,2048]

  float* out = (float*)d_out;
  float* var_out = out + (size_t)NTOK * HID;

  // ws layout
  char* ws = (char*)d_ws;
  int*   counts = (int*)ws;                                   // 32 B
  int*   lists  = (int*)(ws + 1024);                          // 128 KB
  float* probs  = (float*)(ws + 1024 + 131072);               // 128 KB
  int*   top2   = (int*)(ws + 1024 + 2 * 131072);             // 16 KB
  u16*   xbf    = (u16*)(ws + 1024 + 2 * 131072 + 16384);     // 8 MB
  u16*   wbf    = (u16*)((char*)xbf + (size_t)NTOK * DIM * 2);// 32 MB

  hipMemsetAsync(d_out, 0, (size_t)out_size * sizeof(float), stream);

  convert_bf16<<<(NEXP * HID * DIM) / (256 * 8), 256, 0, stream>>>(eW, wbf);
  gate_kernel<<<NTOK / 4, 256, 0, stream>>>(x, gW, gb, probs, top2, xbf);
  route_kernel<<<NEXP, 256, 0, stream>>>(probs, top2, counts, lists, var_out);
  expert_gemm<<<NEXP * (NTOK / BM) * (HID / BN), 512, 0, stream>>>(
      xbf, wbf, eb, counts, lists, out);
}

// Round 7
// 166.359 us; speedup vs baseline: 1.2454x; 1.2445x over previous
//
#include <hip/hip_runtime.h>

// SparseMoE: T=4096, D=1024, E=8, H=2048, top_k=2.
// R7: revert to 128x128 (R3's best geometry), then: (1) persistent blocks
// over a precomputed work-item list (kills ~3072 dead-block dispatches),
// (2) BK=32 double-buffer + prefetch-1 at the SAME 32KB LDS footprint as the
// single-buffered R3 (R4's dbuf lost to occupancy; this one doesn't).
// Swizzled global_load_lds staging, atomic 2-add scatter epilogue (exactly
// 2 commutative fp32 adds per out element onto zeroed buffer -> deterministic).

#define NTOK 4096
#define DIM  1024
#define NEXP 8
#define HID  2048

#define BM 128
#define BN 128
#define BK 32
#define NCB (HID / BN)   // 16 column-blocks per expert

using u16    = unsigned short;
using u16x4  = __attribute__((ext_vector_type(4))) unsigned short;
using u16x8  = __attribute__((ext_vector_type(8))) unsigned short;
using bf16x8 = __attribute__((ext_vector_type(8))) __bf16;
using f32x4  = __attribute__((ext_vector_type(4))) float;

typedef const __attribute__((address_space(1))) unsigned char* gas1p;
typedef __attribute__((address_space(3))) unsigned char* gas3p;

__device__ __forceinline__ void gload16(void* lds, const void* g) {
  __builtin_amdgcn_global_load_lds((gas1p)g, (gas3p)lds, 16, 0, 0);
}

__device__ inline u16 f2bf(float f) {
  union { float f; unsigned u; } v; v.f = f;
  unsigned r = v.u + 0x7fffu + ((v.u >> 16) & 1u);  // RNE, no NaN in this data
  return (u16)(r >> 16);
}

// ---------------- fp32 -> bf16 bulk convert (8 elems/thread) -----------------
__global__ __launch_bounds__(256) void convert_bf16(
    const float* __restrict__ in, u16* __restrict__ out) {
  int i = blockIdx.x * 256 + threadIdx.x;
  const float4* p = (const float4*)in + (size_t)i * 2;
  float4 a = p[0], b = p[1];
  u16x8 r;
  r[0] = f2bf(a.x); r[1] = f2bf(a.y); r[2] = f2bf(a.z); r[3] = f2bf(a.w);
  r[4] = f2bf(b.x); r[5] = f2bf(b.y); r[6] = f2bf(b.z); r[7] = f2bf(b.w);
  *((u16x8*)out + i) = r;
}

// -------- gating: fp64 logits, softmax, top-2 -> ws; also emits xbf ----------
__global__ __launch_bounds__(256) void gate_kernel(
    const float* __restrict__ x, const float* __restrict__ gW,
    const float* __restrict__ gb, float* __restrict__ probs,
    int* __restrict__ top2, u16* __restrict__ xbf) {
  const int wave = threadIdx.x >> 6;
  const int lane = threadIdx.x & 63;
  const int t = blockIdx.x * 4 + wave;

  const float4* xrow = (const float4*)(x + (size_t)t * DIM);
  double acc[NEXP];
#pragma unroll
  for (int e = 0; e < NEXP; ++e) acc[e] = 0.0;

#pragma unroll
  for (int c = 0; c < 4; ++c) {
    int idx = c * 64 + lane;          // float4 index; elems 4*idx..4*idx+3
    float4 xv = xrow[idx];
    u16x4 bv;
    bv[0] = f2bf(xv.x); bv[1] = f2bf(xv.y); bv[2] = f2bf(xv.z); bv[3] = f2bf(xv.w);
    *(u16x4*)(xbf + (size_t)t * DIM + 4 * idx) = bv;   // fused convert_x
#pragma unroll
    for (int e = 0; e < NEXP; ++e) {
      float4 wv = ((const float4*)(gW + (size_t)e * DIM))[idx];
      acc[e] += (double)xv.x * wv.x + (double)xv.y * wv.y +
                (double)xv.z * wv.z + (double)xv.w * wv.w;
    }
  }
#pragma unroll
  for (int e = 0; e < NEXP; ++e) {
    double v = acc[e];
#pragma unroll
    for (int off = 32; off > 0; off >>= 1) v += __shfl_down(v, off);
    acc[e] = v;
  }

  if (lane == 0) {
    double logits[NEXP];
#pragma unroll
    for (int e = 0; e < NEXP; ++e) logits[e] = acc[e] + (double)gb[e];
    double m = logits[0];
#pragma unroll
    for (int e = 1; e < NEXP; ++e) m = fmax(m, logits[e]);
    double p[NEXP], s = 0.0;
#pragma unroll
    for (int e = 0; e < NEXP; ++e) { p[e] = exp(logits[e] - m); s += p[e]; }
#pragma unroll
    for (int e = 0; e < NEXP; ++e) p[e] /= s;

    int i1 = 0;
#pragma unroll
    for (int e = 1; e < NEXP; ++e) if (p[e] > p[i1]) i1 = e;
    int i2 = (i1 == 0) ? 1 : 0;
#pragma unroll
    for (int e = 0; e < NEXP; ++e) {
      if (e != i1 && p[e] > p[i2]) i2 = e;
    }

#pragma unroll
    for (int e = 0; e < NEXP; ++e) probs[(size_t)t * NEXP + e] = (float)p[e];
    top2[t] = i1 | (i2 << 4);
  }
}

// ------- route: per-expert stable compaction (ballot prefix) + fp64 variance -
__global__ __launch_bounds__(256) void route_kernel(
    const float* __restrict__ probs, const int* __restrict__ top2,
    int* __restrict__ counts, int* __restrict__ lists,
    float* __restrict__ var_out) {
  const int e = blockIdx.x;
  const int tid = threadIdx.x;
  const int lane = tid & 63;
  const int wave = tid >> 6;

  __shared__ int wsum[4];
  __shared__ double ds[4], dq[4];

  double s = 0.0, q = 0.0;
  int base = 0;

  for (int c = 0; c < NTOK / 256; ++c) {
    int t = c * 256 + tid;
    float p = probs[(size_t)t * NEXP + e];
    s += (double)p;
    q += (double)p * (double)p;

    int m = top2[t];
    bool f = ((m & 15) == e) || (((m >> 4) & 15) == e);
    unsigned long long bal = __ballot(f);
    int before = __popcll(bal & ((1ull << lane) - 1ull));
    if (lane == 0) wsum[wave] = __popcll(bal);
    __syncthreads();
    int woff = 0;
#pragma unroll
    for (int w = 0; w < 4; ++w) if (w < wave) woff += wsum[w];
    int ctotal = wsum[0] + wsum[1] + wsum[2] + wsum[3];
    if (f) lists[e * NTOK + base + woff + before] = t;
    base += ctotal;
    __syncthreads();
  }
  if (tid == 0) counts[e] = base;

#pragma unroll
  for (int off = 32; off > 0; off >>= 1) {
    s += __shfl_down(s, off);
    q += __shfl_down(q, off);
  }
  if (lane == 0) { ds[wave] = s; dq[wave] = q; }
  __syncthreads();
  if (tid == 0) {
    double S = ds[0] + ds[1] + ds[2] + ds[3];
    double Q = dq[0] + dq[1] + dq[2] + dq[3];
    var_out[e] = (float)((Q - S * S / (double)NTOK) / (double)(NTOK - 1));
  }
}

// ------- build work-item list: deterministic enumeration of real tiles -------
// item = e | (rb << 4) | (cb << 12); only tiles with rb*BM < counts[e].
__global__ __launch_bounds__(256) void build_items(
    const int* __restrict__ counts, int* __restrict__ items,
    int* __restrict__ qlen) {
  __shared__ int off[NEXP];
  const int tid = threadIdx.x;
  if (tid == 0) {
    int o = 0;
#pragma unroll
    for (int e = 0; e < NEXP; ++e) {
      off[e] = o;
      o += ((counts[e] + BM - 1) / BM) * NCB;
    }
    *qlen = o;
  }
  __syncthreads();
#pragma unroll
  for (int e = 0; e < NEXP; ++e) {
    const int ni = ((counts[e] + BM - 1) / BM) * NCB;
    for (int i = tid; i < ni; i += 256) {
      int rb = i / NCB, cb = i % NCB;
      items[off[e] + i] = e | (rb << 4) | (cb << 12);
    }
  }
}

// --- persistent gathered GEMM: 128x128, BK=32 dbuf (32KB LDS), prefetch-1 ---
// LDS per operand per buffer: [128 rows][32 cols] bf16, 64B/row = 4 16B-chunks;
// swizzle stored_c16 = c16 ^ (row&3). global_load_lds writes linearly; global
// source carries the inverse (same) XOR.
__global__ __launch_bounds__(256, 3) void expert_gemm(
    const u16* __restrict__ xbf, const u16* __restrict__ wbf,
    const float* __restrict__ eb, const int* __restrict__ counts,
    const int* __restrict__ lists, const int* __restrict__ items,
    const int* __restrict__ qlen, float* __restrict__ out) {
  __shared__ u16 As[2][BM * BK];   // 2 x 8 KB
  __shared__ u16 Bs[2][BN * BK];   // 2 x 8 KB
  __shared__ int tok[BM];

  const int tid  = threadIdx.x;
  const int wave = tid >> 6;
  const int lane = tid & 63;
  const int wm = (wave >> 1) * 64;
  const int wn = (wave & 1) * 64;
  const int lr = lane & 15;
  const int hk = lane >> 4;        // k-chunk 0..3
  const int nq = *qlen;

  for (int it = blockIdx.x; it < nq; it += gridDim.x) {
    const int item = items[it];
    const int e  = item & 15;
    const int rb = (item >> 4) & 255;
    const int cb = item >> 12;
    const int cnt = counts[e];

    __syncthreads();               // tok/LDS reuse guard across items
    if (tid < BM) {
      int gi = rb * BM + tid;
      tok[tid] = (gi < cnt) ? lists[e * NTOK + gi] : -1;
    }
    __syncthreads();

    // staging: 2 A-chunks + 2 B-chunks of 16B per thread (512 chunks/operand)
    const u16* asrc[2];
    const u16* bsrc[2];
    int ldsoff[2];
#pragma unroll
    for (int j = 0; j < 2; ++j) {
      const int idx = j * 256 + tid;          // chunk index in [0,512)
      const int row = idx >> 2;               // 4 chunks per row
      const int c16 = (idx & 3) ^ (row & 3);  // inverse swizzle on source
      int tr = tok[row]; if (tr < 0) tr = 0;  // clamped; row discarded later
      asrc[j] = xbf + (size_t)tr * DIM + c16 * 8;
      bsrc[j] = wbf + ((size_t)e * HID + (size_t)cb * BN + row) * DIM + c16 * 8;
      ldsoff[j] = j * 2048 + wave * 512;      // wave-uniform base (u16 units)
    }

#define STAGE(buf, k0)                                                        \
  do {                                                                        \
    _Pragma("unroll")                                                         \
    for (int j = 0; j < 2; ++j) gload16(&As[buf][ldsoff[j]], asrc[j] + (k0)); \
    _Pragma("unroll")                                                         \
    for (int j = 0; j < 2; ++j) gload16(&Bs[buf][ldsoff[j]], bsrc[j] + (k0)); \
  } while (0)

    f32x4 acc[4][4];
#pragma unroll
    for (int m = 0; m < 4; ++m)
#pragma unroll
      for (int n = 0; n < 4; ++n) acc[m][n] = (f32x4)(0.0f);

    STAGE(0, 0);
    __syncthreads();               // vmcnt(0) drain + barrier

    int cur = 0;
    for (int kt = 0; kt < DIM / BK; ++kt) {   // 32 iters
      if (kt + 1 < DIM / BK) STAGE(cur ^ 1, (kt + 1) * BK);  // prefetch next

      bf16x8 fa[4], fb[4];
#pragma unroll
      for (int m = 0; m < 4; ++m) {
        const int row = wm + m * 16 + lr;
        const int c16 = hk ^ (row & 3);
        fa[m] = *(const bf16x8*)&As[cur][row * 32 + c16 * 8];
      }
#pragma unroll
      for (int n = 0; n < 4; ++n) {
        const int row = wn + n * 16 + lr;
        const int c16 = hk ^ (row & 3);
        fb[n] = *(const bf16x8*)&Bs[cur][row * 32 + c16 * 8];
      }

#pragma unroll
      for (int m = 0; m < 4; ++m)
#pragma unroll
        for (int n = 0; n < 4; ++n)
          acc[m][n] = __builtin_amdgcn_mfma_f32_16x16x32_bf16(
              fa[m], fb[n], acc[m][n], 0, 0, 0);

      __syncthreads();             // one drain+barrier per K-tile
      cur ^= 1;
    }
#undef STAGE

    // epilogue: out[token, h] += 0.5*(dot + bias)  (2 commutative adds/elem)
#pragma unroll
    for (int n = 0; n < 4; ++n) {
      const int hcol = cb * BN + wn + n * 16 + lr;
      const float bias = eb[e * HID + hcol];
#pragma unroll
      for (int m = 0; m < 4; ++m) {
#pragma unroll
        for (int i = 0; i < 4; ++i) {
          int rloc = wm + m * 16 + hk * 4 + i;   // C/D: row=(lane>>4)*4+i
          int tr = tok[rloc];
          if (tr >= 0)
            atomicAdd(&out[(size_t)tr * HID + hcol], 0.5f * (acc[m][n][i] + bias));
        }
      }
    }
  }
}

extern "C" void kernel_launch(void* const* d_in, const int* in_sizes, int n_in,
                              void* d_out, int out_size, void* d_ws, size_t ws_size,
                              hipStream_t stream) {
  const float* x  = (const float*)d_in[0];   // [4096,1024]
  const float* gW = (const float*)d_in[1];   // [8,1024]
  const float* gb = (const float*)d_in[2];   // [8]
  const float* eW = (const float*)d_in[3];   // [8,2048,1024]
  const float* eb = (const float*)d_in[4];   // [8,2048]

  float* out = (float*)d_out;
  float* var_out = out + (size_t)NTOK * HID;

  // ws layout
  char* ws = (char*)d_ws;
  int*   counts = (int*)ws;                                   // 32 B
  int*   qlen   = (int*)(ws + 64);
  int*   lists  = (int*)(ws + 1024);                          // 128 KB
  float* probs  = (float*)(ws + 1024 + 131072);               // 128 KB
  int*   top2   = (int*)(ws + 1024 + 2 * 131072);             // 16 KB
  int*   items  = (int*)(ws + 1024 + 2 * 131072 + 16384);     // 8 KB (<=1152)
  u16*   xbf    = (u16*)(ws + 294912);                        // 8 MB
  u16*   wbf    = (u16*)((char*)xbf + (size_t)NTOK * DIM * 2);// 32 MB

  hipMemsetAsync(d_out, 0, (size_t)out_size * sizeof(float), stream);

  convert_bf16<<<(NEXP * HID * DIM) / (256 * 8), 256, 0, stream>>>(eW, wbf);
  gate_kernel<<<NTOK / 4, 256, 0, stream>>>(x, gW, gb, probs, top2, xbf);
  route_kernel<<<NEXP, 256, 0, stream>>>(probs, top2, counts, lists, var_out);
  build_items<<<1, 256, 0, stream>>>(counts, items, qlen);
  expert_gemm<<<768, 256, 0, stream>>>(
      xbf, wbf, eb, counts, lists, items, qlen, out);
}

// Round 8
// 109.148 us; speedup vs baseline: 1.8982x; 1.5242x over previous
//
#include <hip/hip_runtime.h>

// SparseMoE: T=4096, D=1024, E=8, H=2048, top_k=2.
// R8: A/B test on the epilogue. GEMM = R3's exact best structure (128x128,
// BK=64 single-buffer, swizzled global_load_lds, 0 bank conflicts). Epilogue
// changed from 16.8M fp32 atomicAdds (64MB L2 RMW — suspected hidden floor
// under R3..R7) to plain bf16 stores into per-(slot,token) partials, plus a
// memory-bound combine kernel (out = 0.5*(p0+p1+b1+b2)). No atomics anywhere.

#define NTOK 4096
#define DIM  1024
#define NEXP 8
#define HID  2048

#define BM 128
#define BN 128
#define BK 64

using u16    = unsigned short;
using u16x4  = __attribute__((ext_vector_type(4))) unsigned short;
using u16x8  = __attribute__((ext_vector_type(8))) unsigned short;
using bf16x8 = __attribute__((ext_vector_type(8))) __bf16;
using f32x4  = __attribute__((ext_vector_type(4))) float;

typedef const __attribute__((address_space(1))) unsigned char* gas1p;
typedef __attribute__((address_space(3))) unsigned char* gas3p;

__device__ __forceinline__ void gload16(void* lds, const void* g) {
  __builtin_amdgcn_global_load_lds((gas1p)g, (gas3p)lds, 16, 0, 0);
}

__device__ inline u16 f2bf(float f) {
  union { float f; unsigned u; } v; v.f = f;
  unsigned r = v.u + 0x7fffu + ((v.u >> 16) & 1u);  // RNE, no NaN in this data
  return (u16)(r >> 16);
}
__device__ inline float bf2f(u16 b) {
  union { unsigned u; float f; } v; v.u = ((unsigned)b) << 16; return v.f;
}

// ---------------- fp32 -> bf16 bulk convert (8 elems/thread) -----------------
__global__ __launch_bounds__(256) void convert_bf16(
    const float* __restrict__ in, u16* __restrict__ out) {
  int i = blockIdx.x * 256 + threadIdx.x;
  const float4* p = (const float4*)in + (size_t)i * 2;
  float4 a = p[0], b = p[1];
  u16x8 r;
  r[0] = f2bf(a.x); r[1] = f2bf(a.y); r[2] = f2bf(a.z); r[3] = f2bf(a.w);
  r[4] = f2bf(b.x); r[5] = f2bf(b.y); r[6] = f2bf(b.z); r[7] = f2bf(b.w);
  *((u16x8*)out + i) = r;
}

// -------- gating: fp64 logits, softmax, top-2 -> ws; also emits xbf ----------
__global__ __launch_bounds__(256) void gate_kernel(
    const float* __restrict__ x, const float* __restrict__ gW,
    const float* __restrict__ gb, float* __restrict__ probs,
    int* __restrict__ top2, u16* __restrict__ xbf) {
  const int wave = threadIdx.x >> 6;
  const int lane = threadIdx.x & 63;
  const int t = blockIdx.x * 4 + wave;

  const float4* xrow = (const float4*)(x + (size_t)t * DIM);
  double acc[NEXP];
#pragma unroll
  for (int e = 0; e < NEXP; ++e) acc[e] = 0.0;

#pragma unroll
  for (int c = 0; c < 4; ++c) {
    int idx = c * 64 + lane;          // float4 index; elems 4*idx..4*idx+3
    float4 xv = xrow[idx];
    u16x4 bv;
    bv[0] = f2bf(xv.x); bv[1] = f2bf(xv.y); bv[2] = f2bf(xv.z); bv[3] = f2bf(xv.w);
    *(u16x4*)(xbf + (size_t)t * DIM + 4 * idx) = bv;   // fused convert_x
#pragma unroll
    for (int e = 0; e < NEXP; ++e) {
      float4 wv = ((const float4*)(gW + (size_t)e * DIM))[idx];
      acc[e] += (double)xv.x * wv.x + (double)xv.y * wv.y +
                (double)xv.z * wv.z + (double)xv.w * wv.w;
    }
  }
#pragma unroll
  for (int e = 0; e < NEXP; ++e) {
    double v = acc[e];
#pragma unroll
    for (int off = 32; off > 0; off >>= 1) v += __shfl_down(v, off);
    acc[e] = v;
  }

  if (lane == 0) {
    double logits[NEXP];
#pragma unroll
    for (int e = 0; e < NEXP; ++e) logits[e] = acc[e] + (double)gb[e];
    double m = logits[0];
#pragma unroll
    for (int e = 1; e < NEXP; ++e) m = fmax(m, logits[e]);
    double p[NEXP], s = 0.0;
#pragma unroll
    for (int e = 0; e < NEXP; ++e) { p[e] = exp(logits[e] - m); s += p[e]; }
#pragma unroll
    for (int e = 0; e < NEXP; ++e) p[e] /= s;

    int i1 = 0;
#pragma unroll
    for (int e = 1; e < NEXP; ++e) if (p[e] > p[i1]) i1 = e;
    int i2 = (i1 == 0) ? 1 : 0;
#pragma unroll
    for (int e = 0; e < NEXP; ++e) {
      if (e != i1 && p[e] > p[i2]) i2 = e;
    }

#pragma unroll
    for (int e = 0; e < NEXP; ++e) probs[(size_t)t * NEXP + e] = (float)p[e];
    top2[t] = i1 | (i2 << 4);
  }
}

// ------- route: per-expert stable compaction (ballot prefix) + fp64 variance -
__global__ __launch_bounds__(256) void route_kernel(
    const float* __restrict__ probs, const int* __restrict__ top2,
    int* __restrict__ counts, int* __restrict__ lists,
    float* __restrict__ var_out) {
  const int e = blockIdx.x;
  const int tid = threadIdx.x;
  const int lane = tid & 63;
  const int wave = tid >> 6;

  __shared__ int wsum[4];
  __shared__ double ds[4], dq[4];

  double s = 0.0, q = 0.0;
  int base = 0;

  for (int c = 0; c < NTOK / 256; ++c) {
    int t = c * 256 + tid;
    float p = probs[(size_t)t * NEXP + e];
    s += (double)p;
    q += (double)p * (double)p;

    int m = top2[t];
    bool f = ((m & 15) == e) || (((m >> 4) & 15) == e);
    unsigned long long bal = __ballot(f);
    int before = __popcll(bal & ((1ull << lane) - 1ull));
    if (lane == 0) wsum[wave] = __popcll(bal);
    __syncthreads();
    int woff = 0;
#pragma unroll
    for (int w = 0; w < 4; ++w) if (w < wave) woff += wsum[w];
    int ctotal = wsum[0] + wsum[1] + wsum[2] + wsum[3];
    if (f) lists[e * NTOK + base + woff + before] = t;
    base += ctotal;
    __syncthreads();
  }
  if (tid == 0) counts[e] = base;

#pragma unroll
  for (int off = 32; off > 0; off >>= 1) {
    s += __shfl_down(s, off);
    q += __shfl_down(q, off);
  }
  if (lane == 0) { ds[wave] = s; dq[wave] = q; }
  __syncthreads();
  if (tid == 0) {
    double S = ds[0] + ds[1] + ds[2] + ds[3];
    double Q = dq[0] + dq[1] + dq[2] + dq[3];
    var_out[e] = (float)((Q - S * S / (double)NTOK) / (double)(NTOK - 1));
  }
}

// --------- gathered expert GEMM: R3 structure, epilogue templated ------------
// LDS tile (A and B): logical [128 rows][64 cols] bf16 row-major, 16B-chunk
// swizzle stored_c16 = c16 ^ (row&7). global_load_lds writes LDS linearly;
// global source carries the inverse (same) XOR.
// USE_PARTIAL=1: plain bf16 stores to partial[k][token][h] (k = slot in top2).
// USE_PARTIAL=0: legacy atomicAdd path (ws too small fallback).
template <int USE_PARTIAL>
__global__ __launch_bounds__(256, 2) void expert_gemm(
    const u16* __restrict__ xbf, const u16* __restrict__ wbf,
    const float* __restrict__ eb, const int* __restrict__ counts,
    const int* __restrict__ lists, const int* __restrict__ top2,
    u16* __restrict__ pbf, float* __restrict__ out) {
  __shared__ u16 As[BM * BK];   // 16 KB
  __shared__ u16 Bs[BN * BK];   // 16 KB
  __shared__ int tok[BM];
  __shared__ int kslot[BM];

  const int bid = blockIdx.x;
  const int e  = bid >> 9;          // 512 blocks/expert: 32 rb x 16 cb
  const int rb = (bid >> 4) & 31;
  const int cb = bid & 15;
  const int cnt = counts[e];
  if (rb * BM >= cnt) return;

  const int tid  = threadIdx.x;
  const int wave = tid >> 6;
  const int lane = tid & 63;

  if (tid < BM) {
    int gi = rb * BM + tid;
    int tr = (gi < cnt) ? lists[e * NTOK + gi] : -1;
    tok[tid] = tr;
    kslot[tid] = (tr >= 0 && (top2[tr] & 15) == e) ? 0 : 1;
  }
  __syncthreads();

  // ---- staging precompute: 4 A-issues + 4 B-issues of 16B per thread ----
  const u16* asrc[4];
  const u16* bsrc[4];
  int ldsoff[4];
#pragma unroll
  for (int j = 0; j < 4; ++j) {
    const int idx  = (j * 4 + wave) * 64 + lane;  // 16B-chunk index in [0,1024)
    const int row  = idx >> 3;
    const int c16  = (idx & 7) ^ (row & 7);       // inverse swizzle on source
    int tr = tok[row]; if (tr < 0) tr = 0;        // clamped; row discarded later
    asrc[j] = xbf + (size_t)tr * DIM + c16 * 8;
    bsrc[j] = wbf + ((size_t)e * HID + (size_t)cb * BN + row) * DIM + c16 * 8;
    ldsoff[j] = (j * 4 + wave) * 512;             // wave-uniform base
  }

  const int wm = (wave >> 1) * 64;
  const int wn = (wave & 1) * 64;
  const int lr = lane & 15;
  const int hk = lane >> 4;        // k-group 0..3

  f32x4 acc[4][4];
#pragma unroll
  for (int m = 0; m < 4; ++m)
#pragma unroll
    for (int n = 0; n < 4; ++n) acc[m][n] = (f32x4)(0.0f);

  for (int k0 = 0; k0 < DIM; k0 += BK) {
#pragma unroll
    for (int j = 0; j < 4; ++j) gload16(&As[ldsoff[j]], asrc[j] + k0);
#pragma unroll
    for (int j = 0; j < 4; ++j) gload16(&Bs[ldsoff[j]], bsrc[j] + k0);

    __syncthreads();   // vmcnt(0) drain + barrier

    bf16x8 fa[2][4], fb[2][4];
#pragma unroll
    for (int kk = 0; kk < 2; ++kk) {
#pragma unroll
      for (int m = 0; m < 4; ++m) {
        const int row = wm + m * 16 + lr;
        const int c16 = (kk * 4 + hk) ^ (row & 7);
        fa[kk][m] = *(const bf16x8*)&As[row * 64 + c16 * 8];
      }
#pragma unroll
      for (int n = 0; n < 4; ++n) {
        const int row = wn + n * 16 + lr;
        const int c16 = (kk * 4 + hk) ^ (row & 7);
        fb[kk][n] = *(const bf16x8*)&Bs[row * 64 + c16 * 8];
      }
    }

#pragma unroll
    for (int kk = 0; kk < 2; ++kk)
#pragma unroll
      for (int m = 0; m < 4; ++m)
#pragma unroll
        for (int n = 0; n < 4; ++n)
          acc[m][n] = __builtin_amdgcn_mfma_f32_16x16x32_bf16(
              fa[kk][m], fb[kk][n], acc[m][n], 0, 0, 0);

    __syncthreads();
  }

  // ---- epilogue ----
#pragma unroll
  for (int n = 0; n < 4; ++n) {
    const int hcol = cb * BN + wn + n * 16 + lr;
    const float bias = eb[e * HID + hcol];
    (void)bias;
#pragma unroll
    for (int m = 0; m < 4; ++m) {
#pragma unroll
      for (int i = 0; i < 4; ++i) {
        int rloc = wm + m * 16 + hk * 4 + i;   // C/D: row=(lane>>4)*4+i
        int tr = tok[rloc];
        if (tr >= 0) {
          if (USE_PARTIAL) {
            pbf[((size_t)kslot[rloc] * NTOK + tr) * HID + hcol] =
                f2bf(acc[m][n][i]);
          } else {
            atomicAdd(&out[(size_t)tr * HID + hcol],
                      0.5f * (acc[m][n][i] + bias));
          }
        }
      }
    }
  }
}

// ---- combine: out[t] = 0.5*(p0 + p1 + b_e1 + b_e2); fully memory-bound -----
__global__ __launch_bounds__(256) void combine_kernel(
    const u16* __restrict__ pbf, const int* __restrict__ top2,
    const float* __restrict__ eb, float* __restrict__ out) {
  const int t = blockIdx.x;
  const int h = threadIdx.x * 8;
  const int m2 = top2[t];
  const int e1 = m2 & 15, e2 = (m2 >> 4) & 15;

  u16x8 p0 = *(const u16x8*)&pbf[(size_t)t * HID + h];
  u16x8 p1 = *(const u16x8*)&pbf[((size_t)NTOK + t) * HID + h];
  const float4* b1 = (const float4*)&eb[e1 * HID + h];
  const float4* b2 = (const float4*)&eb[e2 * HID + h];
  float4 b1a = b1[0], b1b = b1[1], b2a = b2[0], b2b = b2[1];

  float4 o0, o1;
  o0.x = 0.5f * (bf2f(p0[0]) + bf2f(p1[0]) + b1a.x + b2a.x);
  o0.y = 0.5f * (bf2f(p0[1]) + bf2f(p1[1]) + b1a.y + b2a.y);
  o0.z = 0.5f * (bf2f(p0[2]) + bf2f(p1[2]) + b1a.z + b2a.z);
  o0.w = 0.5f * (bf2f(p0[3]) + bf2f(p1[3]) + b1a.w + b2a.w);
  o1.x = 0.5f * (bf2f(p0[4]) + bf2f(p1[4]) + b1b.x + b2b.x);
  o1.y = 0.5f * (bf2f(p0[5]) + bf2f(p1[5]) + b1b.y + b2b.y);
  o1.z = 0.5f * (bf2f(p0[6]) + bf2f(p1[6]) + b1b.z + b2b.z);
  o1.w = 0.5f * (bf2f(p0[7]) + bf2f(p1[7]) + b1b.w + b2b.w);

  float4* po = (float4*)&out[(size_t)t * HID + h];
  po[0] = o0; po[1] = o1;
}

extern "C" void kernel_launch(void* const* d_in, const int* in_sizes, int n_in,
                              void* d_out, int out_size, void* d_ws, size_t ws_size,
                              hipStream_t stream) {
  const float* x  = (const float*)d_in[0];   // [4096,1024]
  const float* gW = (const float*)d_in[1];   // [8,1024]
  const float* gb = (const float*)d_in[2];   // [8]
  const float* eW = (const float*)d_in[3];   // [8,2048,1024]
  const float* eb = (const float*)d_in[4];   // [8,2048]

  float* out = (float*)d_out;
  float* var_out = out + (size_t)NTOK * HID;

  // ws layout
  char* ws = (char*)d_ws;
  int*   counts = (int*)ws;                                   // 32 B
  int*   lists  = (int*)(ws + 1024);                          // 128 KB
  float* probs  = (float*)(ws + 1024 + 131072);               // 128 KB
  int*   top2   = (int*)(ws + 1024 + 2 * 131072);             // 16 KB
  u16*   xbf    = (u16*)(ws + 294912);                        // 8 MB
  u16*   wbf    = (u16*)((char*)xbf + (size_t)NTOK * DIM * 2);// 32 MB
  u16*   pbf    = (u16*)((char*)wbf + (size_t)NEXP * HID * DIM * 2);  // 32 MB

  const size_t need = 294912 + (size_t)NTOK * DIM * 2 +
                      (size_t)NEXP * HID * DIM * 2 +
                      (size_t)2 * NTOK * HID * 2;
  const bool use_partial = (ws_size >= need);

  convert_bf16<<<(NEXP * HID * DIM) / (256 * 8), 256, 0, stream>>>(eW, wbf);
  gate_kernel<<<NTOK / 4, 256, 0, stream>>>(x, gW, gb, probs, top2, xbf);
  route_kernel<<<NEXP, 256, 0, stream>>>(probs, top2, counts, lists, var_out);

  if (use_partial) {
    expert_gemm<1><<<NEXP * (NTOK / BM) * (HID / BN), 256, 0, stream>>>(
        xbf, wbf, eb, counts, lists, top2, pbf, out);
    combine_kernel<<<NTOK, 256, 0, stream>>>(pbf, top2, eb, out);
  } else {
    hipMemsetAsync(d_out, 0, (size_t)out_size * sizeof(float), stream);
    expert_gemm<0><<<NEXP * (NTOK / BM) * (HID / BN), 256, 0, stream>>>(
        xbf, wbf, eb, counts, lists, top2, pbf, out);
  }
}